// Round 9
// baseline (2139.110 us; speedup 1.0000x reference)
//
#include <hip/hip_runtime.h>
#include <hip/hip_bf16.h>
#include <math.h>

#define LRELU_SLOPE 0.2f
typedef __hip_bfloat16 bf16;
typedef __hip_bfloat162 bf16x2;

typedef short s8v __attribute__((ext_vector_type(8)));   // 8 bf16 (4 VGPRs)
typedef float f4v __attribute__((ext_vector_type(4)));   // MFMA acc

__device__ __forceinline__ float lrelu(float v) { return v > 0.f ? v : LRELU_SLOPE * v; }
__device__ __forceinline__ float b2f(short b) {
  return __uint_as_float(((unsigned)(unsigned short)b) << 16);
}

__device__ __forceinline__ void st2(bf16* p, float x, float y) {
  float2 f{x, y};
  *(bf16x2*)p = __float22bfloat162_rn(f);
}
__device__ __forceinline__ void st2(float* p, float x, float y) {
  *(float2*)p = float2{x, y};
}

// nontemporal variants: streaming output shouldn't evict the h gather set
__device__ __forceinline__ void st2_nt(bf16* p, float x, float y) {
  float2 f{x, y};
  bf16x2 v = __float22bfloat162_rn(f);
  __builtin_nontemporal_store(*(unsigned int*)&v, (unsigned int*)p);
}
__device__ __forceinline__ void st2_nt(float* p, float x, float y) {
  __builtin_nontemporal_store(x, p);
  __builtin_nontemporal_store(y, p + 1);
}

// ---------------- zero helper (avoid hipMemsetAsync in capture) ----------------

__global__ void k_zero(unsigned int* __restrict__ p, long n) {
  long i = (long)blockIdx.x * blockDim.x + threadIdx.x;
  if (i < n) p[i] = 0u;
}

__global__ void k_zero_out(float* __restrict__ out, int n) {
  int i = blockIdx.x * blockDim.x + threadIdx.x;
  if (i < n) out[i] = 0.f;
}

// ---------------- dtype prep: x -> bf16, W -> bf16 transposed ----------------

__global__ void k_cvt(const float* __restrict__ x, bf16* __restrict__ xb, long n) {
  long i = (long)blockIdx.x * blockDim.x + threadIdx.x;
  if (i < n) xb[i] = __float2bfloat16(x[i]);
}

// W[K][NN] (f32) -> Wt[NN][K] (bf16)
__global__ void k_tw(const float* __restrict__ W, bf16* __restrict__ Wt, int K, int NN) {
  int i = blockIdx.x * blockDim.x + threadIdx.x;
  if (i >= K * NN) return;
  int k = i / NN, n = i - k * NN;
  Wt[(size_t)n * K + k] = __float2bfloat16(W[i]);
}

// ---------------- preprocessing: counting-sort edges by dst ----------------

__global__ void k_hist(const int* __restrict__ dst, int* __restrict__ deg, int E, int Et) {
  int e = blockIdx.x * blockDim.x + threadIdx.x;
  if (e >= Et) return;
  int d = (e < E) ? dst[e] : (e - E);   // self-loops appended
  atomicAdd(&deg[d], 1);
}

__global__ void k_hist1(const int* __restrict__ idx, int* __restrict__ deg, int n) {
  int i = blockIdx.x * blockDim.x + threadIdx.x;
  if (i < n) atomicAdd(&deg[idx[i]], 1);
}

__global__ void k_scan1(const int* __restrict__ deg, int* __restrict__ offs,
                        int* __restrict__ bsum, int n) {
  __shared__ int sd[256];
  int t = threadIdx.x;
  int base = blockIdx.x * 1024 + t * 4;
  int v[4]; int tsum = 0;
#pragma unroll
  for (int i = 0; i < 4; ++i) { v[i] = (base + i < n) ? deg[base + i] : 0; tsum += v[i]; }
  sd[t] = tsum;
  __syncthreads();
  for (int off = 1; off < 256; off <<= 1) {
    int x = (t >= off) ? sd[t - off] : 0;
    __syncthreads();
    sd[t] += x;
    __syncthreads();
  }
  int excl = sd[t] - tsum;
#pragma unroll
  for (int i = 0; i < 4; ++i) { if (base + i < n) offs[base + i] = excl; excl += v[i]; }
  if (t == 255) bsum[blockIdx.x] = sd[255];
}

__global__ void k_scan2(int* bsum, int nb) {
  if (threadIdx.x == 0 && blockIdx.x == 0) {
    int run = 0;
    for (int i = 0; i < nb; ++i) { int t = bsum[i]; bsum[i] = run; run += t; }
  }
}

__global__ void k_scan3(int* __restrict__ offs, const int* __restrict__ bsum, int n, int total) {
  int t = threadIdx.x;
  int base = blockIdx.x * 1024 + t * 4;
  int add = bsum[blockIdx.x];
#pragma unroll
  for (int i = 0; i < 4; ++i) if (base + i < n) offs[base + i] += add;
  if (blockIdx.x == 0 && t == 0) offs[n] = total;
}

__global__ void k_scatter(const int* __restrict__ src, const int* __restrict__ dst,
                          const int* __restrict__ offs, int* __restrict__ cur,
                          int* __restrict__ ssrc, int E, int Et) {
  int e = blockIdx.x * blockDim.x + threadIdx.x;
  if (e >= Et) return;
  int s, d;
  if (e < E) { s = src[e]; d = dst[e]; } else { s = d = e - E; }
  int pos = offs[d] + atomicAdd(&cur[d], 1);
  ssrc[pos] = s;
}

// ---- bf16 MFMA GEMM + fused attention-logit epilogue ----
// C[M,NN=H*128] = A[M,K] @ Wt[NN,K]^T, written HEAD-INTERLEAVED: C[n][f*H+hd].
// Epilogue also accumulates al_s[n][hd] += sum_f h*as, al_d likewise, via
// quad-reduce over the 16 col-lanes + atomicAdd (al_* must be pre-zeroed).

template <int H>
__global__ __launch_bounds__(256) void k_gemm_mfma(const bf16* __restrict__ A,
                                                   const bf16* __restrict__ Wt,
                                                   bf16* __restrict__ C,
                                                   const float* __restrict__ as,
                                                   const float* __restrict__ ad,
                                                   float* __restrict__ al_s,
                                                   float* __restrict__ al_d,
                                                   int K) {
  constexpr int NN = H * 128;
  __shared__ __align__(16) short sA[64 * 64];   // 8 KB, 64 rows x 64 cols bf16
  int t = threadIdx.x;
  int wv = t >> 6, lane = t & 63;
  int quad = lane >> 4, l15 = lane & 15;
  size_t bm0 = (size_t)blockIdx.x * 64;
  int bn0 = blockIdx.y * 64;
  const bf16* Ab = A + bm0 * K;
  const bf16* Bp = Wt + (size_t)(bn0 + wv * 16 + l15) * K;  // this lane's weight row
  f4v acc[4] = {f4v{0,0,0,0}, f4v{0,0,0,0}, f4v{0,0,0,0}, f4v{0,0,0,0}};

  for (int kb = 0; kb < K; kb += 64) {
#pragma unroll
    for (int j = 0; j < 2; ++j) {
      int idx = j * 256 + t;
      int row = idx >> 3, p = idx & 7;
      int c = p ^ (row & 7);                  // global 16B-chunk landing at pos p
      const bf16* g = Ab + (size_t)row * K + kb + c * 8;
      __builtin_amdgcn_global_load_lds(
          (const __attribute__((address_space(1))) void*)g,
          (__attribute__((address_space(3))) void*)((char*)sA + (size_t)(j * 256 + wv * 64) * 16),
          16, 0, 0);
    }
    __syncthreads();
#pragma unroll
    for (int kk = 0; kk < 2; ++kk) {
      s8v bfrag = *(const s8v*)(Bp + kb + kk * 32 + quad * 8);
#pragma unroll
      for (int ms = 0; ms < 4; ++ms) {
        int row = ms * 16 + l15;
        int pos = (kk * 4 + quad) ^ (row & 7);
        s8v afrag = *(const s8v*)((const char*)sA + (size_t)row * 128 + pos * 16);
        acc[ms] = __builtin_amdgcn_mfma_f32_16x16x32_bf16(afrag, bfrag, acc[ms], 0, 0, 0);
      }
    }
    __syncthreads();
  }
  // C/D layout: col = lane&15, row = quad*4 + reg  [m89/m91 verified]
  int coln = bn0 + wv * 16 + l15;
  int f = coln & 127, hd = coln >> 7;       // 16-col group never crosses a head boundary
  int cix = f * H + hd;                      // head-interleaved column
  float asv = as[coln], adv = ad[coln];
#pragma unroll
  for (int ms = 0; ms < 4; ++ms)
#pragma unroll
    for (int r = 0; r < 4; ++r) {
      float v = acc[ms][r];
      size_t row = bm0 + ms * 16 + quad * 4 + r;
      C[row * NN + cix] = __float2bfloat16(v);
      float vs = v * asv, vd = v * adv;
#pragma unroll
      for (int off = 1; off <= 8; off <<= 1) {
        vs += __shfl_xor(vs, off, 64);
        vd += __shfl_xor(vd, off, 64);
      }
      if (l15 == 0) {
        atomicAdd(&al_s[row * H + hd], vs);
        atomicAdd(&al_d[row * H + hd], vd);
      }
    }
}

// -------- fused segment-softmax + weighted aggregation: one wave per node --------
// No max pass: softmax is shift-invariant; logits are O(20) << 88 so unnormalized
// exp(min(e,80)) is exact (clamp binds only where ref would overflow).
// Per 64-edge chunk: lane e computes exp once (lane-parallel), den via wave-reduce,
// stashes {src, ex[H]} in LDS; serial 8-deep loop reads edge records via
// same-address ds_read (broadcast) and gathers 12B/edge (head-interleaved h:
// 2 feats x 3 heads contiguous -> one line, one addr calc).

template <int H, typename OT>
__global__ __launch_bounds__(256) void k_attn_agg(const bf16* __restrict__ hbuf,
                           const int* __restrict__ ssrc,
                           const int* __restrict__ offs, const float* __restrict__ al_s,
                           const float* __restrict__ al_d, const float* __restrict__ bias,
                           OT* __restrict__ out, int N) {
  constexpr int SW = (H > 1) ? 4 : 2;
  __shared__ __align__(16) float stash[4][64 * SW];
  int n = (blockIdx.x * blockDim.x + threadIdx.x) >> 6;
  int lane = threadIdx.x & 63;
  if (n >= N) return;
  float* st = stash[threadIdx.x >> 6];
  int start = offs[n], end = offs[n + 1];
  float ald[H];
#pragma unroll
  for (int hd = 0; hd < H; ++hd) ald[hd] = al_d[n * H + hd];

  int f0 = lane * 2;
  float den[H], accx[H], accy[H];
#pragma unroll
  for (int hd = 0; hd < H; ++hd) { den[hd] = 0.f; accx[hd] = 0.f; accy[hd] = 0.f; }

  for (int cb = start; cb < end; cb += 64) {
    int cl = end - cb; if (cl > 64) cl = 64;
    // lane-parallel alpha (one exp per edge per head total), unnormalized
    int mys = (lane < cl) ? ssrc[cb + lane] : 0;
    float myex[H];
#pragma unroll
    for (int hd = 0; hd < H; ++hd) {
      float e = lrelu(al_s[mys * H + hd] + ald[hd]);
      float ex = __expf(fminf(e, 80.f));
      myex[hd] = (lane < cl) ? ex : 0.f;
    }
    // den via wave reduce (result uniform across lanes)
#pragma unroll
    for (int hd = 0; hd < H; ++hd) {
      float d = myex[hd];
#pragma unroll
      for (int off = 32; off; off >>= 1) d += __shfl_xor(d, off, 64);
      den[hd] += d;
    }
    // stash this chunk's edge records (wave-private region; wave-synchronous)
    __builtin_amdgcn_wave_barrier();
    if (H > 1) {
      float4 s4{__int_as_float(mys), myex[0], myex[H > 1 ? 1 : 0], myex[H > 1 ? 2 : 0]};
      *(float4*)&st[lane * 4] = s4;
    } else {
      float2 s2{__int_as_float(mys), myex[0]};
      *(float2*)&st[lane * 2] = s2;
    }
    asm volatile("s_waitcnt lgkmcnt(0)" ::: "memory");
    __builtin_amdgcn_wave_barrier();

    for (int r = 0; r < cl; r += 8) {
      int su[8];
      float a[8][H];
#pragma unroll
      for (int u = 0; u < 8; ++u) {
        if (H > 1) {
          float4 ed = *(const float4*)&st[(r + u) * 4];
          su[u] = __float_as_int(ed.x);
          a[u][0] = ed.y;
          a[u][H > 1 ? 1 : 0] = ed.z;
          a[u][H > 1 ? 2 : 0] = ed.w;
        } else {
          float2 ed = *(const float2*)&st[(r + u) * 2];
          su[u] = __float_as_int(ed.x);
          a[u][0] = ed.y;
        }
      }
      if (H > 1) {
        // head-interleaved gather: 6 contiguous bf16 (12B) per edge per lane
        bf16x2 v0[8], v1[8], v2[8];
#pragma unroll
        for (int u = 0; u < 8; ++u) {
          const bf16* hp = hbuf + (size_t)su[u] * (H * 128) + f0 * H;
          v0[u] = *(const bf16x2*)(hp);
          v1[u] = *(const bf16x2*)(hp + 2);
          v2[u] = *(const bf16x2*)(hp + 4);
        }
#pragma unroll
        for (int u = 0; u < 8; ++u) {
          // v0=(f0,h0),(f0,h1)  v1=(f0,h2),(f1,h0)  v2=(f1,h1),(f1,h2)
          float2 p0 = __bfloat1622float2(v0[u]);
          float2 p1 = __bfloat1622float2(v1[u]);
          float2 p2 = __bfloat1622float2(v2[u]);
          accx[0] += a[u][0] * p0.x;
          accx[H > 1 ? 1 : 0] += a[u][H > 1 ? 1 : 0] * p0.y;
          accx[H > 1 ? 2 : 0] += a[u][H > 1 ? 2 : 0] * p1.x;
          accy[0] += a[u][0] * p1.y;
          accy[H > 1 ? 1 : 0] += a[u][H > 1 ? 1 : 0] * p2.x;
          accy[H > 1 ? 2 : 0] += a[u][H > 1 ? 2 : 0] * p2.y;
        }
      } else {
        bf16x2 v[8];
#pragma unroll
        for (int u = 0; u < 8; ++u)
          v[u] = *(const bf16x2*)(hbuf + (size_t)su[u] * 128 + f0);
#pragma unroll
        for (int u = 0; u < 8; ++u) {
          float2 fv = __bfloat1622float2(v[u]);
          accx[0] += a[u][0] * fv.x;
          accy[0] += a[u][0] * fv.y;
        }
      }
    }
  }
  // output in concat-major layout [n][hd*128+f] (GEMM-A contract)
#pragma unroll
  for (int hd = 0; hd < H; ++hd) {
    float r = 1.f / (den[hd] + 1e-16f);
    float ox = lrelu(accx[hd] * r + bias[hd * 128 + f0]);
    float oy = lrelu(accy[hd] * r + bias[hd * 128 + f0 + 1]);
    st2_nt(&out[((size_t)n * H + hd) * 128 + f0], ox, oy);
  }
}

// ---------------- global mean pool: one wave per graph, no atomics ----------------

__global__ void k_pool(const float* __restrict__ h, const int* __restrict__ goffs,
                       float* __restrict__ out, int G) {
  int g = (blockIdx.x * blockDim.x + threadIdx.x) >> 6;
  int lane = threadIdx.x & 63;
  if (g >= G) return;
  int s = goffs[g], e = goffs[g + 1];
  float ax = 0.f, ay = 0.f;
  for (int n = s; n < e; ++n) {
    float2 v = *(const float2*)&h[(size_t)n * 128 + lane * 2];
    ax += v.x; ay += v.y;
  }
  float c = fmaxf((float)(e - s), 1.f);
  st2(&out[(size_t)g * 128 + lane * 2], ax / c, ay / c);
}

// ---------------- host launcher ----------------

extern "C" void kernel_launch(void* const* d_in, const int* in_sizes, int n_in,
                              void* d_out, int out_size, void* d_ws, size_t ws_size,
                              hipStream_t stream) {
  const float* x   = (const float*)d_in[0];
  const int*   ei  = (const int*)d_in[1];
  const int*   bat = (const int*)d_in[2];
  const float* W1  = (const float*)d_in[3];
  const float* a1s = (const float*)d_in[4];
  const float* a1d = (const float*)d_in[5];
  const float* b1  = (const float*)d_in[6];
  const float* W2  = (const float*)d_in[7];
  const float* a2s = (const float*)d_in[8];
  const float* a2d = (const float*)d_in[9];
  const float* b2  = (const float*)d_in[10];
  const float* W3  = (const float*)d_in[11];
  const float* a3s = (const float*)d_in[12];
  const float* a3d = (const float*)d_in[13];
  const float* b3  = (const float*)d_in[14];
  float* out = (float*)d_out;

  const int N = in_sizes[2];          // 200000
  const int E = in_sizes[1] / 2;      // 1600000
  const int Et = E + N;               // with self-loops
  const int G = out_size / 128;       // 5000

  // ---- workspace carve (bf16 intermediates) ----
  char* p = (char*)d_ws;
  auto carve = [&](size_t bytes) { void* r = (void*)p; p += (bytes + 255) & ~(size_t)255; return r; };
  bf16*  bufA   = (bf16*)carve((size_t)N * 384 * 2);   // agg out / GEMM A; also hosts xb & fp32 layer-3 out
  bf16*  bufB   = (bf16*)carve((size_t)N * 384 * 2);   // GEMM output h (head-interleaved)
  float* al_s   = (float*)carve((size_t)N * 3 * 4);    // adjacent to al_d: zeroed together
  float* al_d   = (float*)carve((size_t)N * 3 * 4);
  int*   ssrc   = (int*)carve((size_t)Et * 4);
  int*   offs   = (int*)carve((size_t)(N + 1) * 4);
  int*   deg    = (int*)carve((size_t)N * 4);
  int*   cur    = (int*)carve((size_t)N * 4);
  int*   bsum   = (int*)carve(4096 * 4);
  int*   gdeg   = (int*)carve((size_t)G * 4);
  int*   goffs  = (int*)carve((size_t)(G + 1) * 4);
  bf16*  Wt1    = (bf16*)carve((size_t)384 * 128 * 2);
  bf16*  Wt2    = (bf16*)carve((size_t)384 * 384 * 2);
  bf16*  Wt3    = (bf16*)carve((size_t)128 * 384 * 2);
  size_t need = (size_t)(p - (char*)d_ws);

  if (ws_size < need) {
    k_zero_out<<<(out_size + 255) / 256, 256, 0, stream>>>(out, out_size);
    return;
  }

  const int* esrc = ei;
  const int* edst = ei + E;

  int ebl = (Et + 255) / 256;
  int NB = (N + 1023) / 1024;
  int GB = (G + 1023) / 1024;
  int nodeWaveBlocks = (N * 64 + 255) / 256;
  int alZeroBlocks = (N * 6 + 255) / 256;

  // ---- prep: weight transpose+cast, x cast (xb aliases bufA) ----
  bf16* xb = bufA;
  k_cvt<<<((long)N * 128 + 255) / 256, 256, 0, stream>>>(x, xb, (long)N * 128);
  k_tw<<<(128 * 384 + 255) / 256, 256, 0, stream>>>(W1, Wt1, 128, 384);
  k_tw<<<(384 * 384 + 255) / 256, 256, 0, stream>>>(W2, Wt2, 384, 384);
  k_tw<<<(384 * 128 + 255) / 256, 256, 0, stream>>>(W3, Wt3, 384, 128);

  // ---- sort edges by dst ----
  k_zero<<<(N + 255) / 256, 256, 0, stream>>>((unsigned int*)deg, N);
  k_hist<<<ebl, 256, 0, stream>>>(edst, deg, E, Et);
  k_scan1<<<NB, 256, 0, stream>>>(deg, offs, bsum, N);
  k_scan2<<<1, 64, 0, stream>>>(bsum, NB);
  k_scan3<<<NB, 256, 0, stream>>>(offs, bsum, N, Et);
  k_zero<<<(N + 255) / 256, 256, 0, stream>>>((unsigned int*)cur, N);
  k_scatter<<<ebl, 256, 0, stream>>>(esrc, edst, offs, cur, ssrc, E, Et);

  // ---- graph offsets for pool (batch is sorted) ----
  k_zero<<<(G + 255) / 256, 256, 0, stream>>>((unsigned int*)gdeg, G);
  k_hist1<<<(N + 255) / 256, 256, 0, stream>>>(bat, gdeg, N);
  k_scan1<<<GB, 256, 0, stream>>>(gdeg, goffs, bsum, G);
  k_scan2<<<1, 64, 0, stream>>>(bsum, GB);
  k_scan3<<<GB, 256, 0, stream>>>(goffs, bsum, G, N);

  dim3 g6(N / 64, 6), g2(N / 64, 2);

  // ---- layer 1: xb[N,128] @ W1 -> bufB (interleaved) + al ----
  k_zero<<<alZeroBlocks, 256, 0, stream>>>((unsigned int*)al_s, (long)N * 6);
  k_gemm_mfma<3><<<g6, 256, 0, stream>>>(xb, Wt1, bufB, a1s, a1d, al_s, al_d, 128);
  k_attn_agg<3, bf16><<<nodeWaveBlocks, 256, 0, stream>>>(bufB, ssrc, offs, al_s, al_d, b1, bufA, N);

  // ---- layer 2: bufA[N,384] @ W2 -> bufB (interleaved) + al ----
  k_zero<<<alZeroBlocks, 256, 0, stream>>>((unsigned int*)al_s, (long)N * 6);
  k_gemm_mfma<3><<<g6, 256, 0, stream>>>(bufA, Wt2, bufB, a2s, a2d, al_s, al_d, 384);
  k_attn_agg<3, bf16><<<nodeWaveBlocks, 256, 0, stream>>>(bufB, ssrc, offs, al_s, al_d, b2, bufA, N);

  // ---- layer 3: bufA[N,384] @ W3 -> bufB[N,128] + al, heads=1, fp32 agg out ----
  k_zero<<<alZeroBlocks, 256, 0, stream>>>((unsigned int*)al_s, (long)N * 6);
  k_gemm_mfma<1><<<g2, 256, 0, stream>>>(bufA, Wt3, bufB, a3s, a3d, al_s, al_d, 384);
  float* out3 = (float*)bufA;
  k_attn_agg<1, float><<<nodeWaveBlocks, 256, 0, stream>>>(bufB, ssrc, offs, al_s, al_d, b3, out3, N);

  // ---- global mean pool: segmented, atomic-free ----
  k_pool<<<(G * 64 + 255) / 256, 256, 0, stream>>>(out3, goffs, out, G);
}